// Round 13
// baseline (5514.829 us; speedup 1.0000x reference)
//
#include <hip/hip_runtime.h>

typedef __attribute__((ext_vector_type(8))) short bf16x8;
typedef __attribute__((ext_vector_type(4))) float f32x4;

#define MFMA_B16(A,B,C) __builtin_amdgcn_mfma_f32_16x16x32_bf16((A),(B),(C),0,0,0)

// ---- fragment layout constants (units: fragments of 1KB = 64 lanes * 8 bf16) ----
#define FO_ENC1 0
#define FO_PRI1 48
#define FO_DEC1 88
#define FO_GIH  136
#define FO_GHH  184
#define FO_ENC2 280
#define FO_PRI2 312
#define FO_DEC2 344
#define FO_MS   376
#define FO_DECMS 408
#define NFRAG   412

#define MS 200
#define TS 136

__device__ __forceinline__ unsigned short f2bf(float f) {
  union { float f; unsigned u; } v; v.f = f;
  unsigned r = (v.u + 0x7fffu + ((v.u >> 16) & 1u)) >> 16;
  return (unsigned short)r;
}
__device__ __forceinline__ float bf2f(unsigned short h) {
  union { unsigned u; float f; } v; v.u = ((unsigned)h) << 16;
  return v.f;
}
__device__ __forceinline__ float sigm_(float x) { return 1.f / (1.f + __expf(-x)); }
__device__ __forceinline__ float tanh_(float x) {
  x = fminf(fmaxf(x, -15.f), 15.f);
  float e = __expf(-2.f * x);
  return (1.f - e) / (1.f + e);
}
__device__ __forceinline__ float splus_(float x) {
  return fmaxf(x, 0.f) + log1pf(__expf(-fabsf(x)));
}

// ============================ PREP KERNEL ============================
// Master activation k-layout: [x:0..1 | z:2..33 | y:34..43 | pad:44..63 | h:64..191]
// Fragment (64 lanes x 8 bf16): lane l, elem j -> B[mk = kb*32 + (l>>4)*8 + j][n = nt*16 + (l&15)]
__global__ void prep_kernel(const float* __restrict__ ew1, const float* __restrict__ pw1,
                            const float* __restrict__ dw1, const float* __restrict__ wih,
                            const float* __restrict__ whh, const float* __restrict__ ew2,
                            const float* __restrict__ pw2, const float* __restrict__ dw2,
                            const float* __restrict__ emw, const float* __restrict__ esw,
                            const float* __restrict__ pmw, const float* __restrict__ psw,
                            const float* __restrict__ dmw, const float* __restrict__ dsw,
                            unsigned short* __restrict__ ws)
{
  int blk = blockIdx.x;
  int a = blk / NFRAG, f = blk % NFRAG;
  int l = threadIdx.x, lg = l >> 4, ln = l & 15;
  float v[8];

  if (f < FO_PRI1) {                       // enc1: [x, y, h]
    int fi = f, nt = fi / 6, kb = fi % 6, n = nt * 16 + ln;
#pragma unroll
    for (int j = 0; j < 8; ++j) {
      int mk = kb * 32 + lg * 8 + j;
      int r = (mk < 2) ? mk : (mk >= 34 && mk < 44) ? 2 + (mk - 34)
            : (mk >= 64) ? 12 + (mk - 64) : -1;
      v[j] = (r >= 0) ? ew1[((size_t)a * 140 + r) * 128 + n] : 0.f;
    }
  } else if (f < FO_DEC1) {                // pri1: [y, h]
    int fi = f - FO_PRI1, nt = fi / 5, kb = 1 + fi % 5, n = nt * 16 + ln;
#pragma unroll
    for (int j = 0; j < 8; ++j) {
      int mk = kb * 32 + lg * 8 + j;
      int r = (mk >= 34 && mk < 44) ? (mk - 34) : (mk >= 64) ? 10 + (mk - 64) : -1;
      v[j] = (r >= 0) ? pw1[((size_t)a * 138 + r) * 128 + n] : 0.f;
    }
  } else if (f < FO_GIH) {                 // dec1: [y, z, h]
    int fi = f - FO_DEC1, nt = fi / 6, kb = fi % 6, n = nt * 16 + ln;
#pragma unroll
    for (int j = 0; j < 8; ++j) {
      int mk = kb * 32 + lg * 8 + j;
      int r = (mk >= 2 && mk < 34) ? 10 + (mk - 2) : (mk >= 34 && mk < 44) ? (mk - 34)
            : (mk >= 64) ? 42 + (mk - 64) : -1;
      v[j] = (r >= 0) ? dw1[((size_t)a * 170 + r) * 128 + n] : 0.f;
    }
  } else if (f < FO_GHH) {                 // gru_ih: [x, z], N=384
    int fi = f - FO_GIH, nt = fi / 2, kb = fi % 2, n = nt * 16 + ln;
#pragma unroll
    for (int j = 0; j < 8; ++j) {
      int mk = kb * 32 + lg * 8 + j;
      v[j] = (mk < 34) ? wih[((size_t)a * 34 + mk) * 384 + n] : 0.f;
    }
  } else if (f < FO_ENC2) {                // gru_hh: K=128, N=384
    int fi = f - FO_GHH, nt = fi / 4, kb = fi % 4, n = nt * 16 + ln;
#pragma unroll
    for (int j = 0; j < 8; ++j) {
      int r = kb * 32 + lg * 8 + j;
      v[j] = whh[((size_t)a * 128 + r) * 384 + n];
    }
  } else if (f < FO_DEC2) {                // enc2 / pri2
    int fi = f - FO_ENC2;
    const float* W = (fi < 32) ? ew2 : pw2;
    fi &= 31;
    int nt = fi / 4, kb = fi % 4, n = nt * 16 + ln;
#pragma unroll
    for (int j = 0; j < 8; ++j) {
      int r = kb * 32 + lg * 8 + j;
      v[j] = W[((size_t)a * 128 + r) * 128 + n];
    }
  } else if (f < FO_MS) {                  // dec2
    int fi = f - FO_DEC2, nt = fi / 4, kb = fi % 4, n = nt * 16 + ln;
#pragma unroll
    for (int j = 0; j < 8; ++j) {
      int r = kb * 32 + lg * 8 + j;
      v[j] = dw2[((size_t)a * 128 + r) * 128 + n];
    }
  } else if (f < FO_DECMS) {               // enc_m / enc_s / pri_m / pri_s (N=32)
    int fi = f - FO_MS, mat = fi / 8, rem = fi % 8, nt = rem / 4, kb = rem % 4;
    int n = nt * 16 + ln;
    const float* W = (mat == 0) ? emw : (mat == 1) ? esw : (mat == 2) ? pmw : psw;
#pragma unroll
    for (int j = 0; j < 8; ++j) {
      int r = kb * 32 + lg * 8 + j;
      v[j] = W[((size_t)a * 128 + r) * 32 + n];
    }
  } else {                                 // dec m/s packed
    int kb = f - FO_DECMS;
#pragma unroll
    for (int j = 0; j < 8; ++j) {
      int r = kb * 32 + lg * 8 + j;
      v[j] = (ln < 2) ? dmw[((size_t)a * 128 + r) * 2 + ln]
           : (ln < 4) ? dsw[((size_t)a * 128 + r) * 2 + (ln - 2)] : 0.f;
    }
  }
  unsigned short* dst = ws + (size_t)blk * 512 + l * 8;
#pragma unroll
  for (int j = 0; j < 8; ++j) dst[j] = f2bf(v[j]);
}

// ============================ MAIN KERNEL ============================
// WAVE-SYNCHRONOUS: grid (32,5), 64 threads = ONE wave per block; 16 rows/block.
// The entire per-step chain runs in a single wave -> ZERO barriers in the t-loop;
// producer->consumer hand-offs are in-wave LDS round-trips (lgkmcnt-ordered).
// VGPR budget at 64-thr block = 512/wave (65536/blockSize rule, R10/R11 measured).
// h(t) lives in registers (C-layout) across steps; ghh/ms/dms pinned in LDS;
// other weights stream from L2 with a pinned loop-variant offset (blocks LICM).
#define LD_FRAG(idx) (*(const bf16x8*)(fal + (size_t)(idx) * 512 + l * 8))

__global__ __launch_bounds__(64, 1) void vrnn_main(
    const float* __restrict__ states, const float* __restrict__ eps,
    const float* __restrict__ eb1, const float* __restrict__ eb2,
    const float* __restrict__ emb, const float* __restrict__ esb,
    const float* __restrict__ pb1, const float* __restrict__ pb2,
    const float* __restrict__ pmb, const float* __restrict__ psb,
    const float* __restrict__ db1, const float* __restrict__ db2,
    const float* __restrict__ dmb, const float* __restrict__ dsb,
    const float* __restrict__ bih, const float* __restrict__ bhh,
    const unsigned short* __restrict__ frags, float* __restrict__ out)
{
  const int a = blockIdx.y;
  const int b0 = blockIdx.x * 16;
  const int l = threadIdx.x, lg = l >> 4, ln = l & 15;

  __shared__ __align__(16) unsigned short ghh_lds[96 * 512];   // 98304 B
  __shared__ __align__(16) unsigned short ms_lds[32 * 512];    // 32768 B
  __shared__ __align__(16) unsigned short dms_lds[4 * 512];    //  4096 B
  __shared__ __align__(16) unsigned short master[16 * MS];     //  6400 B
  __shared__ __align__(16) unsigned short t1buf[16 * TS];      //  4352 B
  __shared__ __align__(16) unsigned short hbuf[16 * TS];
  __shared__ __align__(16) unsigned short hdbuf[16 * TS];

  const unsigned short* fa = frags + (size_t)a * NFRAG * 512;

  // ---- pin LDS weight sets (one-time, single wave)
  {
    const uint4* s1 = (const uint4*)(fa + (size_t)FO_GHH * 512);
    uint4* d1 = (uint4*)ghh_lds;
    for (int i = l; i < 96 * 64; i += 64) d1[i] = s1[i];
    const uint4* s2 = (const uint4*)(fa + (size_t)FO_MS * 512);
    uint4* d2 = (uint4*)ms_lds;
    for (int i = l; i < 32 * 64; i += 64) d2[i] = s2[i];
    const uint4* s3 = (const uint4*)(fa + (size_t)FO_DECMS * 512);
    uint4* d3 = (uint4*)dms_lds;
    for (int i = l; i < 4 * 64; i += 64) d3[i] = s3[i];
  }
  for (int i = l; i < 16 * MS; i += 64) master[i] = 0;

  // ---- biases (all 8 n-tiles, this lane's column n = nt*16+ln)
  float eb1v[8], pb1v[8], eb2v[8], pb2v[8], d1b[8], db2v[8], ghb[3][8];
#pragma unroll
  for (int nt = 0; nt < 8; ++nt) {
    int n = nt * 16 + ln;
    eb1v[nt] = eb1[a * 128 + n]; pb1v[nt] = pb1[a * 128 + n];
    eb2v[nt] = eb2[a * 128 + n]; pb2v[nt] = pb2[a * 128 + n];
    d1b[nt] = db1[a * 128 + n]; db2v[nt] = db2[a * 128 + n];
#pragma unroll
    for (int g = 0; g < 3; ++g)
      ghb[g][nt] = bih[a * 384 + g * 128 + n] + bhh[a * 384 + g * 128 + n];
  }
  float hbme[2], hbse[2], hbmp[2], hbsp[2];
#pragma unroll
  for (int j = 0; j < 2; ++j) {
    hbme[j] = emb[a * 32 + j * 16 + ln]; hbse[j] = esb[a * 32 + j * 16 + ln];
    hbmp[j] = pmb[a * 32 + j * 16 + ln]; hbsp[j] = psb[a * 32 + j * 16 + ln];
  }
  float dmsb = (ln < 2) ? dmb[a * 2 + ln] : (ln < 4) ? dsb[a * 2 + (ln - 2)] : 0.f;

  // ---- stage y(0); x(0)=states[1]; eps(0); xv = x(0) for step-0 NLL
  for (int i = l; i < 160; i += 64) {
    int row = i / 10, c = i - row * 10;
    master[row * MS + 34 + c] = f2bf(states[(size_t)(b0 + row) * 10 + c]);
  }
  if (l < 32) {
    int row = l >> 1, c = l & 1;
    master[row * MS + c] = f2bf(states[((size_t)512 + b0 + row) * 10 + a * 2 + c]);
  }
  float e_cur[2][4];
#pragma unroll
  for (int j = 0; j < 2; ++j)
#pragma unroll
    for (int q = 0; q < 4; ++q)
      e_cur[j][q] = eps[((size_t)(b0 + 4 * lg + q) * 5 + a) * 32 + j * 16 + ln];
  float xv[4];
#pragma unroll
  for (int q = 0; q < 4; ++q)
    xv[q] = states[((size_t)512 + b0 + 4 * lg + q) * 10 + a * 2 + (ln & 1)];

  float h_reg[8][4];
#pragma unroll
  for (int nt = 0; nt < 8; ++nt)
#pragma unroll
    for (int q = 0; q < 4; ++q) h_reg[nt][q] = 0.f;

  float kl = 0.f, nll = 0.f;
  int off = 0;

  for (int t = 0; t < 127; ++t) {
    asm volatile("" : "+v"(off));          // block LICM of loop-"invariant" loads
    const unsigned short* fal  = fa + off;
    const unsigned short* ghhp = ghh_lds + off;
    const unsigned short* msp  = ms_lds + off;

    // ---- A-fragments: h (k-blocks 2..5) and x/z(stale,zero-wt)/y (k-blocks 0,1)
    bf16x8 am_h[4], amA[2];
#pragma unroll
    for (int kb = 0; kb < 4; ++kb)
      am_h[kb] = *(const bf16x8*)&master[ln * MS + (kb + 2) * 32 + lg * 8];
#pragma unroll
    for (int kb = 0; kb < 2; ++kb)
      amA[kb] = *(const bf16x8*)&master[ln * MS + kb * 32 + lg * 8];

    // ---- dec-head of step t-1 + NLL (reads hdbuf written at end of prev step)
    if (t > 0) {
      f32x4 acc = {dmsb, dmsb, dmsb, dmsb};
#pragma unroll
      for (int kb = 0; kb < 4; ++kb) {
        bf16x8 ad = *(const bf16x8*)&hdbuf[ln * TS + kb * 32 + lg * 8];
        bf16x8 bf = *(const bf16x8*)&dms_lds[kb * 512 + l * 8];
        acc = MFMA_B16(ad, bf, acc);
      }
#pragma unroll
      for (int q = 0; q < 4; ++q) {
        float sv = __shfl(splus_(acc[q]), l + 2);
        if (ln < 2) {
          float d = (xv[q] - acc[q]) / sv;
          nll += 0.9189385332f + __logf(sv) + 0.5f * d * d;
        }
      }
    }

    // ---- enc1 -> t1buf
#pragma unroll
    for (int nt = 0; nt < 8; ++nt) {
      f32x4 acc = {eb1v[nt], eb1v[nt], eb1v[nt], eb1v[nt]};
#pragma unroll
      for (int kb = 0; kb < 6; ++kb)
        acc = MFMA_B16(kb < 2 ? amA[kb] : am_h[kb - 2], LD_FRAG(FO_ENC1 + nt * 6 + kb), acc);
#pragma unroll
      for (int q = 0; q < 4; ++q)
        t1buf[(4 * lg + q) * TS + nt * 16 + ln] = f2bf(fmaxf(acc[q], 0.f));
    }
    // ---- enc2 -> hbuf
    {
      bf16x8 at[4];
#pragma unroll
      for (int kb = 0; kb < 4; ++kb)
        at[kb] = *(const bf16x8*)&t1buf[ln * TS + kb * 32 + lg * 8];
#pragma unroll
      for (int nt = 0; nt < 8; ++nt) {
        f32x4 acc = {eb2v[nt], eb2v[nt], eb2v[nt], eb2v[nt]};
#pragma unroll
        for (int kb = 0; kb < 4; ++kb)
          acc = MFMA_B16(at[kb], LD_FRAG(FO_ENC2 + nt * 4 + kb), acc);
#pragma unroll
        for (int q = 0; q < 4; ++q)
          hbuf[(4 * lg + q) * TS + nt * 16 + ln] = f2bf(fmaxf(acc[q], 0.f));
      }
    }
    // ---- enc heads -> em2, es2 (registers)
    f32x4 em2[2], es2[2];
    {
      bf16x8 ah[4];
#pragma unroll
      for (int kb = 0; kb < 4; ++kb)
        ah[kb] = *(const bf16x8*)&hbuf[ln * TS + kb * 32 + lg * 8];
#pragma unroll
      for (int j = 0; j < 2; ++j) {
        f32x4 m = {hbme[j], hbme[j], hbme[j], hbme[j]};
        f32x4 s = {hbse[j], hbse[j], hbse[j], hbse[j]};
#pragma unroll
        for (int kb = 0; kb < 4; ++kb) {
          m = MFMA_B16(ah[kb], *(const bf16x8*)(msp + (size_t)(j * 4 + kb) * 512 + l * 8), m);
          s = MFMA_B16(ah[kb], *(const bf16x8*)(msp + (size_t)(8 + j * 4 + kb) * 512 + l * 8), s);
        }
        em2[j] = m;
#pragma unroll
        for (int q = 0; q < 4; ++q) es2[j][q] = splus_(s[q]);
      }
    }
    // ---- pri1 -> t1buf (reuse)
#pragma unroll
    for (int nt = 0; nt < 8; ++nt) {
      f32x4 acc = {pb1v[nt], pb1v[nt], pb1v[nt], pb1v[nt]};
#pragma unroll
      for (int kb = 0; kb < 5; ++kb)
        acc = MFMA_B16(kb == 0 ? amA[1] : am_h[kb - 1], LD_FRAG(FO_PRI1 + nt * 5 + kb), acc);
#pragma unroll
      for (int q = 0; q < 4; ++q)
        t1buf[(4 * lg + q) * TS + nt * 16 + ln] = f2bf(fmaxf(acc[q], 0.f));
    }
    // ---- pri2 -> hbuf (reuse)
    {
      bf16x8 at[4];
#pragma unroll
      for (int kb = 0; kb < 4; ++kb)
        at[kb] = *(const bf16x8*)&t1buf[ln * TS + kb * 32 + lg * 8];
#pragma unroll
      for (int nt = 0; nt < 8; ++nt) {
        f32x4 acc = {pb2v[nt], pb2v[nt], pb2v[nt], pb2v[nt]};
#pragma unroll
        for (int kb = 0; kb < 4; ++kb)
          acc = MFMA_B16(at[kb], LD_FRAG(FO_PRI2 + nt * 4 + kb), acc);
#pragma unroll
        for (int q = 0; q < 4; ++q)
          hbuf[(4 * lg + q) * TS + nt * 16 + ln] = f2bf(fmaxf(acc[q], 0.f));
      }
    }
    // ---- pri heads + KL (registers); z -> master
    {
      bf16x8 ah[4];
#pragma unroll
      for (int kb = 0; kb < 4; ++kb)
        ah[kb] = *(const bf16x8*)&hbuf[ln * TS + kb * 32 + lg * 8];
#pragma unroll
      for (int j = 0; j < 2; ++j) {
        f32x4 m = {hbmp[j], hbmp[j], hbmp[j], hbmp[j]};
        f32x4 s = {hbsp[j], hbsp[j], hbsp[j], hbsp[j]};
#pragma unroll
        for (int kb = 0; kb < 4; ++kb) {
          m = MFMA_B16(ah[kb], *(const bf16x8*)(msp + (size_t)(16 + j * 4 + kb) * 512 + l * 8), m);
          s = MFMA_B16(ah[kb], *(const bf16x8*)(msp + (size_t)(24 + j * 4 + kb) * 512 + l * 8), s);
        }
#pragma unroll
        for (int q = 0; q < 4; ++q) {
          float ps = splus_(s[q]);
          float es = es2[j][q];
          float dm = em2[j][q] - m[q];
          kl += 0.5f * (2.f * __logf(ps) - 2.f * __logf(es)
                        + (es * es + dm * dm) / (ps * ps) - 1.f);
          master[(4 * lg + q) * MS + 2 + j * 16 + ln] =
            f2bf(em2[j][q] + es * e_cur[j][q]);
        }
      }
    }
    // ---- re-read k-blocks 0,1 with fresh z
    bf16x8 amZ[2];
#pragma unroll
    for (int kb = 0; kb < 2; ++kb)
      amZ[kb] = *(const bf16x8*)&master[ln * MS + kb * 32 + lg * 8];

    // ---- GRU: ghh (LDS) + gih (stream) + elementwise, per n-tile
#pragma unroll
    for (int nt = 0; nt < 8; ++nt) {
      f32x4 g3[3], i3[3];
#pragma unroll
      for (int g = 0; g < 3; ++g) {
        g3[g] = (f32x4){ghb[g][nt], ghb[g][nt], ghb[g][nt], ghb[g][nt]};
        i3[g] = (f32x4){0.f, 0.f, 0.f, 0.f};
      }
#pragma unroll
      for (int kb = 0; kb < 4; ++kb)
#pragma unroll
        for (int g = 0; g < 3; ++g)
          g3[g] = MFMA_B16(am_h[kb],
            *(const bf16x8*)(ghhp + (size_t)((g * 8 + nt) * 4 + kb) * 512 + l * 8), g3[g]);
#pragma unroll
      for (int kb = 0; kb < 2; ++kb)
#pragma unroll
        for (int g = 0; g < 3; ++g)
          i3[g] = MFMA_B16(amZ[kb], LD_FRAG(FO_GIH + (g * 8 + nt) * 2 + kb), i3[g]);
#pragma unroll
      for (int q = 0; q < 4; ++q) {
        float r_ = sigm_(i3[0][q] + g3[0][q]);
        float u_ = sigm_(i3[1][q] + g3[1][q]);
        float n_ = tanh_(i3[2][q] + r_ * g3[2][q]);
        h_reg[nt][q] = (1.f - u_) * n_ + u_ * h_reg[nt][q];
      }
    }

    // ---- dec1 -> t1buf (uses amZ + OLD h via am_h regs)
#pragma unroll
    for (int nt = 0; nt < 8; ++nt) {
      f32x4 acc = {d1b[nt], d1b[nt], d1b[nt], d1b[nt]};
#pragma unroll
      for (int kb = 0; kb < 6; ++kb)
        acc = MFMA_B16(kb < 2 ? amZ[kb] : am_h[kb - 2], LD_FRAG(FO_DEC1 + nt * 6 + kb), acc);
#pragma unroll
      for (int q = 0; q < 4; ++q)
        t1buf[(4 * lg + q) * TS + nt * 16 + ln] = f2bf(fmaxf(acc[q], 0.f));
    }
    // ---- dec2 -> hdbuf (consumed by next step's dec-head / epilogue)
    {
      bf16x8 at[4];
#pragma unroll
      for (int kb = 0; kb < 4; ++kb)
        at[kb] = *(const bf16x8*)&t1buf[ln * TS + kb * 32 + lg * 8];
#pragma unroll
      for (int nt = 0; nt < 8; ++nt) {
        f32x4 acc = {db2v[nt], db2v[nt], db2v[nt], db2v[nt]};
#pragma unroll
        for (int kb = 0; kb < 4; ++kb)
          acc = MFMA_B16(at[kb], LD_FRAG(FO_DEC2 + nt * 4 + kb), acc);
#pragma unroll
        for (int q = 0; q < 4; ++q)
          hdbuf[(4 * lg + q) * TS + nt * 16 + ln] = f2bf(fmaxf(acc[q], 0.f));
      }
    }

    // ---- write new h to master (for next step's A-frags)
#pragma unroll
    for (int nt = 0; nt < 8; ++nt)
#pragma unroll
      for (int q = 0; q < 4; ++q)
        master[(4 * lg + q) * MS + 64 + nt * 16 + ln] = f2bf(h_reg[nt][q]);

    // ---- next-step inputs: xv(t), eps(t+1), y(t+1), x(t+2)
#pragma unroll
    for (int q = 0; q < 4; ++q)
      xv[q] = states[((size_t)(t + 1) * 512 + b0 + 4 * lg + q) * 10 + a * 2 + (ln & 1)];
    if (t < 126) {
#pragma unroll
      for (int j = 0; j < 2; ++j)
#pragma unroll
        for (int q = 0; q < 4; ++q)
          e_cur[j][q] = eps[((size_t)((t + 1) * 512 + b0 + 4 * lg + q) * 5 + a) * 32
                            + j * 16 + ln];
      for (int i = l; i < 160; i += 64) {
        int row = i / 10, c = i - row * 10;
        master[row * MS + 34 + c] =
          f2bf(states[((size_t)(t + 1) * 512 + b0 + row) * 10 + c]);
      }
      if (l < 32) {
        int row = l >> 1, c = l & 1;
        master[row * MS + c] =
          f2bf(states[((size_t)(t + 2) * 512 + b0 + row) * 10 + a * 2 + c]);
      }
    }
  }

  // ---- epilogue: dec-head + NLL for t=126
  {
    f32x4 acc = {dmsb, dmsb, dmsb, dmsb};
#pragma unroll
    for (int kb = 0; kb < 4; ++kb) {
      bf16x8 ad = *(const bf16x8*)&hdbuf[ln * TS + kb * 32 + lg * 8];
      bf16x8 bf = *(const bf16x8*)&dms_lds[kb * 512 + l * 8];
      acc = MFMA_B16(ad, bf, acc);
    }
#pragma unroll
    for (int q = 0; q < 4; ++q) {
      float sv = __shfl(splus_(acc[q]), l + 2);
      if (ln < 2) {
        float d = (xv[q] - acc[q]) / sv;
        nll += 0.9189385332f + __logf(sv) + 0.5f * d * d;
      }
    }
  }

  // ---- wave reduction + atomic
#pragma unroll
  for (int o = 32; o > 0; o >>= 1) {
    kl += __shfl_down(kl, o);
    nll += __shfl_down(nll, o);
  }
  if (l == 0) {
    atomicAdd(out, kl);
    atomicAdd(out + 1, nll);
  }
}

extern "C" void kernel_launch(void* const* d_in, const int* in_sizes, int n_in,
                              void* d_out, int out_size, void* d_ws, size_t ws_size,
                              hipStream_t stream) {
  (void)in_sizes; (void)n_in; (void)out_size; (void)ws_size;
  const float* states = (const float*)d_in[0];
  const float* eps    = (const float*)d_in[1];
  const float* ew1 = (const float*)d_in[2];
  const float* eb1 = (const float*)d_in[3];
  const float* ew2 = (const float*)d_in[4];
  const float* eb2 = (const float*)d_in[5];
  const float* emw = (const float*)d_in[6];
  const float* emb = (const float*)d_in[7];
  const float* esw = (const float*)d_in[8];
  const float* esb = (const float*)d_in[9];
  const float* pw1 = (const float*)d_in[10];
  const float* pb1 = (const float*)d_in[11];
  const float* pw2 = (const float*)d_in[12];
  const float* pb2 = (const float*)d_in[13];
  const float* pmw = (const float*)d_in[14];
  const float* pmb = (const float*)d_in[15];
  const float* psw = (const float*)d_in[16];
  const float* psb = (const float*)d_in[17];
  const float* dw1 = (const float*)d_in[18];
  const float* db1 = (const float*)d_in[19];
  const float* dw2 = (const float*)d_in[20];
  const float* db2 = (const float*)d_in[21];
  const float* dmw = (const float*)d_in[22];
  const float* dmb = (const float*)d_in[23];
  const float* dsw = (const float*)d_in[24];
  const float* dsb = (const float*)d_in[25];
  const float* wih = (const float*)d_in[26];
  const float* whh = (const float*)d_in[27];
  const float* bih = (const float*)d_in[28];
  const float* bhh = (const float*)d_in[29];

  unsigned short* frags = (unsigned short*)d_ws;
  float* out = (float*)d_out;

  hipMemsetAsync(d_out, 0, 2 * sizeof(float), stream);
  prep_kernel<<<dim3(5 * NFRAG), dim3(64), 0, stream>>>(
      ew1, pw1, dw1, wih, whh, ew2, pw2, dw2, emw, esw, pmw, psw, dmw, dsw, frags);
  vrnn_main<<<dim3(32, 5), dim3(64), 0, stream>>>(
      states, eps, eb1, eb2, emb, esb, pb1, pb2, pmb, psb,
      db1, db2, dmb, dsb, bih, bhh, frags, out);
}

// Round 14
// 976.823 us; speedup vs baseline: 5.6457x; 5.6457x over previous
//
#include <hip/hip_runtime.h>

typedef __attribute__((ext_vector_type(8))) short bf16x8;
typedef __attribute__((ext_vector_type(4))) float f32x4;

#define MFMA_B16(A,B,C) __builtin_amdgcn_mfma_f32_16x16x32_bf16((A),(B),(C),0,0,0)

// ---- fragment layout constants (units: fragments of 1KB = 64 lanes * 8 bf16) ----
#define FO_ENC1 0
#define FO_PRI1 48
#define FO_DEC1 88
#define FO_GIH  136
#define FO_GHH  184
#define FO_ENC2 280
#define FO_PRI2 312
#define FO_DEC2 344
#define FO_MS   376
#define FO_DECMS 408
#define NFRAG   412

#define MS 264          // master stride: cols 0-63 xyz region A, 64-191 h, 200-263 xyz region B
#define TS 136

__device__ __forceinline__ unsigned short f2bf(float f) {
  union { float f; unsigned u; } v; v.f = f;
  unsigned r = (v.u + 0x7fffu + ((v.u >> 16) & 1u)) >> 16;
  return (unsigned short)r;
}
__device__ __forceinline__ float bf2f(unsigned short h) {
  union { unsigned u; float f; } v; v.u = ((unsigned)h) << 16;
  return v.f;
}
__device__ __forceinline__ float sigm_(float x) { return 1.f / (1.f + __expf(-x)); }
__device__ __forceinline__ float tanh_(float x) {
  x = fminf(fmaxf(x, -15.f), 15.f);
  float e = __expf(-2.f * x);
  return (1.f - e) / (1.f + e);
}
__device__ __forceinline__ float splus_(float x) {
  return fmaxf(x, 0.f) + log1pf(__expf(-fabsf(x)));
}
__device__ __forceinline__ float ldnt(const float* p) {
  return __builtin_nontemporal_load(p);
}

// ============================ PREP KERNEL ============================
// Master activation k-layout: [x:0..1 | z:2..33 | y:34..43 | pad:44..63 | h:64..191]
__global__ void prep_kernel(const float* __restrict__ ew1, const float* __restrict__ pw1,
                            const float* __restrict__ dw1, const float* __restrict__ wih,
                            const float* __restrict__ whh, const float* __restrict__ ew2,
                            const float* __restrict__ pw2, const float* __restrict__ dw2,
                            const float* __restrict__ emw, const float* __restrict__ esw,
                            const float* __restrict__ pmw, const float* __restrict__ psw,
                            const float* __restrict__ dmw, const float* __restrict__ dsw,
                            unsigned short* __restrict__ ws)
{
  int blk = blockIdx.x;
  int a = blk / NFRAG, f = blk % NFRAG;
  int l = threadIdx.x, lg = l >> 4, ln = l & 15;
  float v[8];

  if (f < FO_PRI1) {                       // enc1: [x, y, h]
    int fi = f, nt = fi / 6, kb = fi % 6, n = nt * 16 + ln;
#pragma unroll
    for (int j = 0; j < 8; ++j) {
      int mk = kb * 32 + lg * 8 + j;
      int r = (mk < 2) ? mk : (mk >= 34 && mk < 44) ? 2 + (mk - 34)
            : (mk >= 64) ? 12 + (mk - 64) : -1;
      v[j] = (r >= 0) ? ew1[((size_t)a * 140 + r) * 128 + n] : 0.f;
    }
  } else if (f < FO_DEC1) {                // pri1: [y, h]
    int fi = f - FO_PRI1, nt = fi / 5, kb = 1 + fi % 5, n = nt * 16 + ln;
#pragma unroll
    for (int j = 0; j < 8; ++j) {
      int mk = kb * 32 + lg * 8 + j;
      int r = (mk >= 34 && mk < 44) ? (mk - 34) : (mk >= 64) ? 10 + (mk - 64) : -1;
      v[j] = (r >= 0) ? pw1[((size_t)a * 138 + r) * 128 + n] : 0.f;
    }
  } else if (f < FO_GIH) {                 // dec1: [y, z, h]
    int fi = f - FO_DEC1, nt = fi / 6, kb = fi % 6, n = nt * 16 + ln;
#pragma unroll
    for (int j = 0; j < 8; ++j) {
      int mk = kb * 32 + lg * 8 + j;
      int r = (mk >= 2 && mk < 34) ? 10 + (mk - 2) : (mk >= 34 && mk < 44) ? (mk - 34)
            : (mk >= 64) ? 42 + (mk - 64) : -1;
      v[j] = (r >= 0) ? dw1[((size_t)a * 170 + r) * 128 + n] : 0.f;
    }
  } else if (f < FO_GHH) {                 // gru_ih: [x, z], N=384
    int fi = f - FO_GIH, nt = fi / 2, kb = fi % 2, n = nt * 16 + ln;
#pragma unroll
    for (int j = 0; j < 8; ++j) {
      int mk = kb * 32 + lg * 8 + j;
      v[j] = (mk < 34) ? wih[((size_t)a * 34 + mk) * 384 + n] : 0.f;
    }
  } else if (f < FO_ENC2) {                // gru_hh: K=128, N=384
    int fi = f - FO_GHH, nt = fi / 4, kb = fi % 4, n = nt * 16 + ln;
#pragma unroll
    for (int j = 0; j < 8; ++j) {
      int r = kb * 32 + lg * 8 + j;
      v[j] = whh[((size_t)a * 128 + r) * 384 + n];
    }
  } else if (f < FO_DEC2) {                // enc2 / pri2
    int fi = f - FO_ENC2;
    const float* W = (fi < 32) ? ew2 : pw2;
    fi &= 31;
    int nt = fi / 4, kb = fi % 4, n = nt * 16 + ln;
#pragma unroll
    for (int j = 0; j < 8; ++j) {
      int r = kb * 32 + lg * 8 + j;
      v[j] = W[((size_t)a * 128 + r) * 128 + n];
    }
  } else if (f < FO_MS) {                  // dec2
    int fi = f - FO_DEC2, nt = fi / 4, kb = fi % 4, n = nt * 16 + ln;
#pragma unroll
    for (int j = 0; j < 8; ++j) {
      int r = kb * 32 + lg * 8 + j;
      v[j] = dw2[((size_t)a * 128 + r) * 128 + n];
    }
  } else if (f < FO_DECMS) {               // enc_m / enc_s / pri_m / pri_s (N=32)
    int fi = f - FO_MS, mat = fi / 8, rem = fi % 8, nt = rem / 4, kb = rem % 4;
    int n = nt * 16 + ln;
    const float* W = (mat == 0) ? emw : (mat == 1) ? esw : (mat == 2) ? pmw : psw;
#pragma unroll
    for (int j = 0; j < 8; ++j) {
      int r = kb * 32 + lg * 8 + j;
      v[j] = W[((size_t)a * 128 + r) * 32 + n];
    }
  } else {                                 // dec m/s packed
    int kb = f - FO_DECMS;
#pragma unroll
    for (int j = 0; j < 8; ++j) {
      int r = kb * 32 + lg * 8 + j;
      v[j] = (ln < 2) ? dmw[((size_t)a * 128 + r) * 2 + ln]
           : (ln < 4) ? dsw[((size_t)a * 128 + r) * 2 + (ln - 2)] : 0.f;
    }
  }
  unsigned short* dst = ws + (size_t)blk * 512 + l * 8;
#pragma unroll
  for (int j = 0; j < 8; ++j) dst[j] = f2bf(v[j]);
}

// ============================ MAIN KERNEL ============================
// grid (32,5), 256 threads = 4 waves, 256 VGPR/wave. 4 barriers/step.
// Recurrent chain: P1(enc1,pri1) | P2(enc2,pri2,ghh) | P3(heads+z; dec2(t-1); staging)
//   | P4(gih+GRU+h; dec1; dec-head(t-1)+NLL; KL; eps/xv loads).
// x/y/z ping-pong between master cols 0-63 (even t) and 200-263 (odd t) so staging
// never races reads. Old-h kept in regs (am_h A-layout, h_reg C-layout) -> no h race.
// dec path lags one step: dec1(t) in P4(t), dec2(t) in P3(t+1), dec-head(t) in P4(t+1).
#define LD_FRAG(idx) (*(const bf16x8*)(fa + (size_t)(idx) * 512 + l * 8))

__global__ __launch_bounds__(256, 1) void vrnn_main(
    const float* __restrict__ states, const float* __restrict__ eps,
    const float* __restrict__ eb1, const float* __restrict__ eb2,
    const float* __restrict__ emb, const float* __restrict__ esb,
    const float* __restrict__ pb1, const float* __restrict__ pb2,
    const float* __restrict__ pmb, const float* __restrict__ psb,
    const float* __restrict__ db1, const float* __restrict__ db2,
    const float* __restrict__ dmb, const float* __restrict__ dsb,
    const float* __restrict__ bih, const float* __restrict__ bhh,
    const unsigned short* __restrict__ frags, float* __restrict__ out)
{
  const int a = blockIdx.y;
  const int b0 = blockIdx.x * 16;
  const int tid = threadIdx.x;
  const int w = tid >> 6, l = tid & 63, lg = l >> 4, ln = l & 15;

  __shared__ __align__(16) unsigned short ghh_lds[96 * 512];   // 98304 B
  __shared__ __align__(16) unsigned short dms_lds[4 * 512];    //  4096 B
  __shared__ __align__(16) unsigned short master[16 * MS];     //  8448 B
  __shared__ __align__(16) unsigned short t1e[16 * TS], t1p[16 * TS];
  __shared__ __align__(16) unsigned short he[16 * TS], hp[16 * TS];
  __shared__ __align__(16) unsigned short t1d[16 * TS], hdbuf[16 * TS]; // 26112 B total
  __shared__ float msbuf[4][16][32];                           //  8192 B
  __shared__ float red[8];

  const unsigned short* fa = frags + (size_t)a * NFRAG * 512;

  // ---- pin LDS weight sets (once)
  {
    const uint4* s1 = (const uint4*)(fa + (size_t)FO_GHH * 512);
    uint4* d1 = (uint4*)ghh_lds;
    for (int i = tid; i < 96 * 64; i += 256) d1[i] = s1[i];
    const uint4* s3 = (const uint4*)(fa + (size_t)FO_DECMS * 512);
    uint4* d3 = (uint4*)dms_lds;
    d3[tid] = s3[tid];
  }
  for (int i = tid; i < 16 * MS; i += 256) master[i] = 0;

  // ---- biases (2 n-tiles per wave)
  float eb1v[2], pb1v[2], eb2v[2], pb2v[2], db2v[2], d1b[2], ghb[3][2];
#pragma unroll
  for (int j = 0; j < 2; ++j) {
    int n = (w + 4 * j) * 16 + ln;
    eb1v[j] = eb1[a * 128 + n]; pb1v[j] = pb1[a * 128 + n];
    eb2v[j] = eb2[a * 128 + n]; pb2v[j] = pb2[a * 128 + n];
    db2v[j] = db2[a * 128 + n]; d1b[j]  = db1[a * 128 + n];
#pragma unroll
    for (int g = 0; g < 3; ++g)
      ghb[g][j] = bih[a * 384 + g * 128 + n] + bhh[a * 384 + g * 128 + n];
  }
  float hbm, hbs, dmsb = 0.f;
  if (w < 2) { hbm = emb[a * 32 + w * 16 + ln]; hbs = esb[a * 32 + w * 16 + ln]; }
  else { hbm = pmb[a * 32 + (w - 2) * 16 + ln]; hbs = psb[a * 32 + (w - 2) * 16 + ln]; }
  if (w == 0) dmsb = (ln < 2) ? dmb[a * 2 + ln] : (ln < 4) ? dsb[a * 2 + (ln - 2)] : 0.f;

  __syncthreads();

  // ---- prime region0: y(0), x(0)=states[1]; eps(0); xv(0) pre-guard
  if (tid < 160) {
    int row = tid / 10, c = tid - row * 10;
    master[row * MS + 34 + c] = f2bf(ldnt(states + (size_t)(b0 + row) * 10 + c));
  }
  if (tid >= 192 && tid < 224) {
    int i = tid - 192, row = i >> 1, c = i & 1;
    master[row * MS + c] = f2bf(ldnt(states + ((size_t)512 + b0 + row) * 10 + a * 2 + c));
  }
  float e_cur[4] = {0.f, 0.f, 0.f, 0.f};
  if (w < 2) {
#pragma unroll
    for (int q = 0; q < 4; ++q)
      e_cur[q] = ldnt(eps + ((size_t)(b0 + 4 * lg + q) * 5 + a) * 32 + w * 16 + ln);
  }
  float xv[4] = {0.f, 0.f, 0.f, 0.f};       // x(t) for NLL(t), loaded in P4(t)
  float h_reg[2][4];
#pragma unroll
  for (int j = 0; j < 2; ++j)
#pragma unroll
    for (int q = 0; q < 4; ++q) h_reg[j][q] = 0.f;
  float kl = 0.f, nll = 0.f;
  f32x4 gh[3][2];
  __syncthreads();

  for (int t = 0; t < 127; ++t) {
    const int base_t = (t & 1) * 200;
    const int base_n = ((t + 1) & 1) * 200;

    // ===== P1: enc1 -> t1e, pri1 -> t1p (n-tiles w, w+4) =====
    bf16x8 amA[2], am_h[4];
#pragma unroll
    for (int kb = 0; kb < 2; ++kb)
      amA[kb] = *(const bf16x8*)&master[ln * MS + base_t + kb * 32 + lg * 8];
#pragma unroll
    for (int kb = 0; kb < 4; ++kb)
      am_h[kb] = *(const bf16x8*)&master[ln * MS + 64 + kb * 32 + lg * 8];
    {
      bf16x8 f1[12], f2[10];
#pragma unroll
      for (int j = 0; j < 2; ++j) {
#pragma unroll
        for (int kb = 0; kb < 6; ++kb) f1[j * 6 + kb] = LD_FRAG(FO_ENC1 + (w + 4 * j) * 6 + kb);
#pragma unroll
        for (int kb = 0; kb < 5; ++kb) f2[j * 5 + kb] = LD_FRAG(FO_PRI1 + (w + 4 * j) * 5 + kb);
      }
#pragma unroll
      for (int j = 0; j < 2; ++j) {
        f32x4 a1 = {eb1v[j], eb1v[j], eb1v[j], eb1v[j]};
        f32x4 a2 = {pb1v[j], pb1v[j], pb1v[j], pb1v[j]};
#pragma unroll
        for (int kb = 0; kb < 6; ++kb)
          a1 = MFMA_B16(kb < 2 ? amA[kb] : am_h[kb - 2], f1[j * 6 + kb], a1);
#pragma unroll
        for (int i = 0; i < 5; ++i)
          a2 = MFMA_B16(i == 0 ? amA[1] : am_h[i - 1], f2[j * 5 + i], a2);
#pragma unroll
        for (int q = 0; q < 4; ++q) {
          t1e[(4 * lg + q) * TS + (w + 4 * j) * 16 + ln] = f2bf(fmaxf(a1[q], 0.f));
          t1p[(4 * lg + q) * TS + (w + 4 * j) * 16 + ln] = f2bf(fmaxf(a2[q], 0.f));
        }
      }
    }
    __syncthreads();

    // ===== P2: enc2 -> he, pri2 -> hp; ghh -> gh regs =====
    {
      bf16x8 g1[8], g2[8];
#pragma unroll
      for (int j = 0; j < 2; ++j)
#pragma unroll
        for (int kb = 0; kb < 4; ++kb) {
          g1[j * 4 + kb] = LD_FRAG(FO_ENC2 + (w + 4 * j) * 4 + kb);
          g2[j * 4 + kb] = LD_FRAG(FO_PRI2 + (w + 4 * j) * 4 + kb);
        }
      bf16x8 ae[4], ap[4];
#pragma unroll
      for (int kb = 0; kb < 4; ++kb) {
        ae[kb] = *(const bf16x8*)&t1e[ln * TS + kb * 32 + lg * 8];
        ap[kb] = *(const bf16x8*)&t1p[ln * TS + kb * 32 + lg * 8];
      }
#pragma unroll
      for (int j = 0; j < 2; ++j) {
        f32x4 a1 = {eb2v[j], eb2v[j], eb2v[j], eb2v[j]};
        f32x4 a2 = {pb2v[j], pb2v[j], pb2v[j], pb2v[j]};
#pragma unroll
        for (int kb = 0; kb < 4; ++kb) {
          a1 = MFMA_B16(ae[kb], g1[j * 4 + kb], a1);
          a2 = MFMA_B16(ap[kb], g2[j * 4 + kb], a2);
        }
#pragma unroll
        for (int q = 0; q < 4; ++q) {
          he[(4 * lg + q) * TS + (w + 4 * j) * 16 + ln] = f2bf(fmaxf(a1[q], 0.f));
          hp[(4 * lg + q) * TS + (w + 4 * j) * 16 + ln] = f2bf(fmaxf(a2[q], 0.f));
        }
      }
      // ghh from pinned LDS (uses am_h = h(t-1) regs)
#pragma unroll
      for (int g = 0; g < 3; ++g)
#pragma unroll
        for (int j = 0; j < 2; ++j) {
          float bv = ghb[g][j];
          gh[g][j] = (f32x4){bv, bv, bv, bv};
        }
#pragma unroll
      for (int kb = 0; kb < 4; ++kb)
#pragma unroll
        for (int g = 0; g < 3; ++g)
#pragma unroll
          for (int j = 0; j < 2; ++j)
            gh[g][j] = MFMA_B16(am_h[kb],
              *(const bf16x8*)&ghh_lds[(size_t)((g * 8 + w + 4 * j) * 4 + kb) * 512 + l * 8],
              gh[g][j]);
    }
    __syncthreads();

    // ===== P3: heads + z; dec2(t-1) -> hdbuf; stage y(t+1)/x(t+1) into base_n =====
    {
      const unsigned short* hs = (w < 2) ? he : hp;
      int mbase = FO_MS + ((w < 2) ? 0 : 16) + (w & 1) * 4;
      bf16x8 fm[4], fs[4];
#pragma unroll
      for (int kb = 0; kb < 4; ++kb) {
        fm[kb] = LD_FRAG(mbase + kb);
        fs[kb] = LD_FRAG(mbase + 8 + kb);
      }
      bf16x8 ah[4];
#pragma unroll
      for (int kb = 0; kb < 4; ++kb)
        ah[kb] = *(const bf16x8*)&hs[ln * TS + kb * 32 + lg * 8];
      f32x4 m = {hbm, hbm, hbm, hbm}, s = {hbs, hbs, hbs, hbs};
#pragma unroll
      for (int kb = 0; kb < 4; ++kb) {
        m = MFMA_B16(ah[kb], fm[kb], m);
        s = MFMA_B16(ah[kb], fs[kb], s);
      }
      if (w < 2) {
#pragma unroll
        for (int q = 0; q < 4; ++q) {
          float es = splus_(s[q]);
          msbuf[0][4 * lg + q][w * 16 + ln] = m[q];
          msbuf[1][4 * lg + q][w * 16 + ln] = es;
          master[(4 * lg + q) * MS + base_t + 2 + w * 16 + ln] = f2bf(m[q] + es * e_cur[q]);
        }
      } else {
#pragma unroll
        for (int q = 0; q < 4; ++q) {
          msbuf[2][4 * lg + q][(w - 2) * 16 + ln] = m[q];
          msbuf[3][4 * lg + q][(w - 2) * 16 + ln] = splus_(s[q]);
        }
      }
      // dec2(t-1): t1d -> hdbuf
      if (t > 0) {
        bf16x8 fd2[8];
#pragma unroll
        for (int j = 0; j < 2; ++j)
#pragma unroll
          for (int kb = 0; kb < 4; ++kb)
            fd2[j * 4 + kb] = LD_FRAG(FO_DEC2 + (w + 4 * j) * 4 + kb);
        bf16x8 ad[4];
#pragma unroll
        for (int kb = 0; kb < 4; ++kb)
          ad[kb] = *(const bf16x8*)&t1d[ln * TS + kb * 32 + lg * 8];
#pragma unroll
        for (int j = 0; j < 2; ++j) {
          f32x4 acc = {db2v[j], db2v[j], db2v[j], db2v[j]};
#pragma unroll
          for (int kb = 0; kb < 4; ++kb) acc = MFMA_B16(ad[kb], fd2[j * 4 + kb], acc);
#pragma unroll
          for (int q = 0; q < 4; ++q)
            hdbuf[(4 * lg + q) * TS + (w + 4 * j) * 16 + ln] = f2bf(fmaxf(acc[q], 0.f));
        }
      }
      // stage next step's y(t+1) and x(t+1)=states[t+2] into the OTHER region
      if (t < 126) {
        if (tid < 160) {
          int row = tid / 10, c = tid - row * 10;
          master[row * MS + base_n + 34 + c] =
            f2bf(ldnt(states + ((size_t)(t + 1) * 512 + b0 + row) * 10 + c));
        }
        if (tid >= 192 && tid < 224) {
          int i = tid - 192, row = i >> 1, c = i & 1;
          master[row * MS + base_n + c] =
            f2bf(ldnt(states + ((size_t)(t + 2) * 512 + b0 + row) * 10 + a * 2 + c));
        }
      }
    }
    __syncthreads();

    // ===== P4: gih+GRU+h; dec1 -> t1d; dec-head(t-1)+NLL; KL; eps/xv loads =====
    {
      bf16x8 amZ[2];
#pragma unroll
      for (int kb = 0; kb < 2; ++kb)
        amZ[kb] = *(const bf16x8*)&master[ln * MS + base_t + kb * 32 + lg * 8];
      // loads first (overlap)
      if (w == 0) {
#pragma unroll
        for (int q = 0; q < 4; ++q)
          xv[q] = ldnt(states + ((size_t)(t + 1) * 512 + b0 + 4 * lg + q) * 10
                       + a * 2 + (ln & 1));
      }
      bf16x8 fd[12], fg[12];
#pragma unroll
      for (int j = 0; j < 2; ++j)
#pragma unroll
        for (int kb = 0; kb < 6; ++kb)
          fd[j * 6 + kb] = LD_FRAG(FO_DEC1 + (w + 4 * j) * 6 + kb);
#pragma unroll
      for (int g = 0; g < 3; ++g)
#pragma unroll
        for (int j = 0; j < 2; ++j)
#pragma unroll
          for (int kb = 0; kb < 2; ++kb)
            fg[g * 4 + j * 2 + kb] = LD_FRAG(FO_GIH + (g * 8 + w + 4 * j) * 2 + kb);

      // dec-head(t-1) + NLL(t-1) on w0
      if (w == 0 && t > 0) {
        f32x4 acc = {dmsb, dmsb, dmsb, dmsb};
#pragma unroll
        for (int kb = 0; kb < 4; ++kb) {
          bf16x8 ad = *(const bf16x8*)&hdbuf[ln * TS + kb * 32 + lg * 8];
          bf16x8 bf = *(const bf16x8*)&dms_lds[kb * 512 + l * 8];
          acc = MFMA_B16(ad, bf, acc);
        }
#pragma unroll
        for (int q = 0; q < 4; ++q) {
          float sv = __shfl(splus_(acc[q]), l + 2);
          if (ln < 2) {
            float d = (xv[q] - acc[q]) / sv;     // xv still holds x(t-1)
            nll += 0.9189385332f + __logf(sv) + 0.5f * d * d;
          }
        }
      }

      // dec1 -> t1d
#pragma unroll
      for (int j = 0; j < 2; ++j) {
        f32x4 acc = {d1b[j], d1b[j], d1b[j], d1b[j]};
#pragma unroll
        for (int kb = 0; kb < 6; ++kb)
          acc = MFMA_B16(kb < 2 ? amZ[kb] : am_h[kb - 2], fd[j * 6 + kb], acc);
#pragma unroll
        for (int q = 0; q < 4; ++q)
          t1d[(4 * lg + q) * TS + (w + 4 * j) * 16 + ln] = f2bf(fmaxf(acc[q], 0.f));
      }
      // gih + GRU + h write (old h from h_reg; master h only for next step's reads)
      f32x4 gi[3][2];
#pragma unroll
      for (int g = 0; g < 3; ++g)
#pragma unroll
        for (int j = 0; j < 2; ++j) gi[g][j] = (f32x4){0.f, 0.f, 0.f, 0.f};
#pragma unroll
      for (int kb = 0; kb < 2; ++kb)
#pragma unroll
        for (int g = 0; g < 3; ++g)
#pragma unroll
          for (int j = 0; j < 2; ++j)
            gi[g][j] = MFMA_B16(amZ[kb], fg[g * 4 + j * 2 + kb], gi[g][j]);
#pragma unroll
      for (int j = 0; j < 2; ++j)
#pragma unroll
        for (int q = 0; q < 4; ++q) {
          float r_ = sigm_(gi[0][j][q] + gh[0][j][q]);
          float u_ = sigm_(gi[1][j][q] + gh[1][j][q]);
          float n_ = tanh_(gi[2][j][q] + r_ * gh[2][j][q]);
          float hn = (1.f - u_) * n_ + u_ * h_reg[j][q];
          h_reg[j][q] = hn;
          master[(4 * lg + q) * MS + 64 + (w + 4 * j) * 16 + ln] = f2bf(hn);
        }
      // KL(t): spread across all 4 waves (4 rows x 32 cols each, 2 elems/lane)
#pragma unroll
      for (int rr = 0; rr < 2; ++rr) {
        int elem = rr * 64 + l;
        int row = w * 4 + (elem >> 5), col = elem & 31;
        float em_ = msbuf[0][row][col], es_ = msbuf[1][row][col];
        float pm_ = msbuf[2][row][col], ps_ = msbuf[3][row][col];
        float dm = em_ - pm_;
        kl += 0.5f * (2.f * __logf(ps_) - 2.f * __logf(es_)
                      + (es_ * es_ + dm * dm) / (ps_ * ps_) - 1.f);
      }
      // eps(t+1)
      if (w < 2 && t < 126) {
#pragma unroll
        for (int q = 0; q < 4; ++q)
          e_cur[q] = ldnt(eps + ((size_t)((t + 1) * 512 + b0 + 4 * lg + q) * 5 + a) * 32
                          + w * 16 + ln);
      }
    }
    __syncthreads();
  }

  // ---- epilogue: dec2(126) then dec-head(126)+NLL(126)
  {
    bf16x8 fd2[8];
#pragma unroll
    for (int j = 0; j < 2; ++j)
#pragma unroll
      for (int kb = 0; kb < 4; ++kb)
        fd2[j * 4 + kb] = LD_FRAG(FO_DEC2 + (w + 4 * j) * 4 + kb);
    bf16x8 ad[4];
#pragma unroll
    for (int kb = 0; kb < 4; ++kb)
      ad[kb] = *(const bf16x8*)&t1d[ln * TS + kb * 32 + lg * 8];
#pragma unroll
    for (int j = 0; j < 2; ++j) {
      f32x4 acc = {db2v[j], db2v[j], db2v[j], db2v[j]};
#pragma unroll
      for (int kb = 0; kb < 4; ++kb) acc = MFMA_B16(ad[kb], fd2[j * 4 + kb], acc);
#pragma unroll
      for (int q = 0; q < 4; ++q)
        hdbuf[(4 * lg + q) * TS + (w + 4 * j) * 16 + ln] = f2bf(fmaxf(acc[q], 0.f));
    }
  }
  __syncthreads();
  if (w == 0) {
    f32x4 acc = {dmsb, dmsb, dmsb, dmsb};
#pragma unroll
    for (int kb = 0; kb < 4; ++kb) {
      bf16x8 ad = *(const bf16x8*)&hdbuf[ln * TS + kb * 32 + lg * 8];
      bf16x8 bf = *(const bf16x8*)&dms_lds[kb * 512 + l * 8];
      acc = MFMA_B16(ad, bf, acc);
    }
#pragma unroll
    for (int q = 0; q < 4; ++q) {
      float sv = __shfl(splus_(acc[q]), l + 2);
      if (ln < 2) {
        float d = (xv[q] - acc[q]) / sv;       // xv = x(126) from P4(126)
        nll += 0.9189385332f + __logf(sv) + 0.5f * d * d;
      }
    }
  }

  // ---- final reduction (4 waves)
#pragma unroll
  for (int off = 32; off > 0; off >>= 1) {
    kl += __shfl_down(kl, off);
    nll += __shfl_down(nll, off);
  }
  if (l == 0) { red[w] = kl; red[4 + w] = nll; }
  __syncthreads();
  if (tid == 0) {
    float K = 0.f, N = 0.f;
#pragma unroll
    for (int i = 0; i < 4; ++i) { K += red[i]; N += red[4 + i]; }
    atomicAdd(out, K);
    atomicAdd(out + 1, N);
  }
}

extern "C" void kernel_launch(void* const* d_in, const int* in_sizes, int n_in,
                              void* d_out, int out_size, void* d_ws, size_t ws_size,
                              hipStream_t stream) {
  (void)in_sizes; (void)n_in; (void)out_size; (void)ws_size;
  const float* states = (const float*)d_in[0];
  const float* eps    = (const float*)d_in[1];
  const float* ew1 = (const float*)d_in[2];
  const float* eb1 = (const float*)d_in[3];
  const float* ew2 = (const float*)d_in[4];
  const float* eb2 = (const float*)d_in[5];
  const float* emw = (const float*)d_in[6];
  const float* emb = (const float*)d_in[7];
  const float* esw = (const float*)d_in[8];
  const float* esb = (const float*)d_in[9];
  const float* pw1 = (const float*)d_in[10];
  const float* pb1 = (const float*)d_in[11];
  const float* pw2 = (const float*)d_in[12];
  const float* pb2 = (const float*)d_in[13];
  const float* pmw = (const float*)d_in[14];
  const float* pmb = (const float*)d_in[15];
  const float* psw = (const float*)d_in[16];
  const float* psb = (const float*)d_in[17];
  const float* dw1 = (const float*)d_in[18];
  const float* db1 = (const float*)d_in[19];
  const float* dw2 = (const float*)d_in[20];
  const float* db2 = (const float*)d_in[21];
  const float* dmw = (const float*)d_in[22];
  const float* dmb = (const float*)d_in[23];
  const float* dsw = (const float*)d_in[24];
  const float* dsb = (const float*)d_in[25];
  const float* wih = (const float*)d_in[26];
  const float* whh = (const float*)d_in[27];
  const float* bih = (const float*)d_in[28];
  const float* bhh = (const float*)d_in[29];

  unsigned short* frags = (unsigned short*)d_ws;
  float* out = (float*)d_out;

  hipMemsetAsync(d_out, 0, 2 * sizeof(float), stream);
  prep_kernel<<<dim3(5 * NFRAG), dim3(64), 0, stream>>>(
      ew1, pw1, dw1, wih, whh, ew2, pw2, dw2, emw, esw, pmw, psw, dmw, dsw, frags);
  vrnn_main<<<dim3(32, 5), dim3(256), 0, stream>>>(
      states, eps, eb1, eb2, emb, esb, pb1, pb2, pmb, psb,
      db1, db2, dmb, dsb, bih, bhh, frags, out);
}